// Round 6
// baseline (278.278 us; speedup 1.0000x reference)
//
#include <hip/hip_runtime.h>
#include <hip/hip_bf16.h>

#define ADAPTERS 40
#define CAPS 3
#define IN_CH 600
#define BSZ 256
#define DCLS 200
#define DMODEL 768

typedef __attribute__((ext_vector_type(8))) short short8;   // 8 bf16
typedef __attribute__((ext_vector_type(4))) float f32x4;
typedef __attribute__((ext_vector_type(4))) float f4v;

// ---------------------------------------------------------------------------
// K1 (MFMA): priors[cap][b][k][d] = sum_c x[b][k][c] * rw[k][cap][c][d]
// f32 inputs split into bf16 hi/lo; D += hi*hi + lo*hi + hi*lo
// (error ~2^-16 relative — f32-equivalent).
// CHANGE vs round 5: tile 128x128 -> 128(b)x64(j), still 512 threads
// -> 420 active blocks (~2 blocks/CU, was 1).  Two co-resident blocks give
// independent barrier domains: block B's waves run through block A's
// __syncthreads rendezvous (the round-3/5 lever, third application).
// LDS 61.4 KB/block (2 fit); __launch_bounds__(512,4) caps VGPR at 128.
// Same per-element chunk order, same MFMA sequence/operand order
// -> bit-identical output.
// ---------------------------------------------------------------------------
#define RP 40          // LDS row pitch in ushorts (32 data + 8 pad = 80 B)
#define NCHUNK 19

__device__ __forceinline__ void split2(float f0, float f1,
                                       unsigned& hi, unsigned& lo) {
    unsigned u0 = __float_as_uint(f0), u1 = __float_as_uint(f1);
    unsigned h0 = u0 & 0xFFFF0000u, h1 = u1 & 0xFFFF0000u;
    hi = (u0 >> 16) | h1;
    float l0 = f0 - __uint_as_float(h0);
    float l1 = f1 - __uint_as_float(h1);
    lo = (__float_as_uint(l0) >> 16) | (__float_as_uint(l1) & 0xFFFF0000u);
}

__global__ __launch_bounds__(512, 4) void k1_priors(
    const float* __restrict__ x,    // [B][A][IN_CH]
    const float* __restrict__ rw,   // [A][CAPS][IN_CH][DCLS]
    const float* __restrict__ tsv,  // [A][A]
    const int* __restrict__ t_p,
    float* __restrict__ priors)     // [CAPS][B][A][DCLS]
{
    int kk = blockIdx.z;            // adapter
    int t = t_p[0];
    if (tsv[t * ADAPTERS + kk] == 0.0f) return;

    int b0 = blockIdx.x * 128;      // 0 or 128
    int j0 = blockIdx.y * 64;       // 0..576

    // double-buffered: A 128 rows, B 64 rows  (total 61.4 KB)
    __shared__ __align__(16) unsigned short Ahi[2][128 * RP];
    __shared__ __align__(16) unsigned short Alo[2][128 * RP];
    __shared__ __align__(16) unsigned short Bhi[2][64 * RP];
    __shared__ __align__(16) unsigned short Blo[2][64 * RP];

    int tid = threadIdx.x;
    int lane = tid & 63, w = tid >> 6;          // w = 0..7
    int lm = lane & 15, lq = lane >> 4;
    int m0w = (w & 1) * 64;                     // b-half
    int n0w = (w >> 1) * 16;                    // j-sixteenth (0,16,32,48)

    // ---- staging thread maps (512 threads) ----
    // A: row = tid>>2 (128 rows), 8 floats at (tid&3)*8
    int a_bi = tid >> 2;
    int a_ci0 = (tid & 3) * 8;
    const float* a_row = x + ((size_t)(b0 + a_bi) * ADAPTERS + kk) * IN_CH;
    // B: row = tid&63 (64 rows, lane-consecutive -> 256B-coalesced rw reads),
    //    4 strided scalars at (tid>>6)*4
    int b_jj = tid & 63;
    int b_ci0 = (tid >> 6) * 4;
    int j = j0 + b_jj;
    bool jvalid = (j < CAPS * DCLS);
    int cap = (j >= 2 * DCLS) ? 2 : ((j >= DCLS) ? 1 : 0);
    int d = j - cap * DCLS;
    const float* b_base = rw + ((size_t)(kk * 3 + cap) * IN_CH) * DCLS + d;

    f32x4 acc[4];
    #pragma unroll
    for (int mt = 0; mt < 4; mt++)
        acc[mt] = (f32x4){0.f, 0.f, 0.f, 0.f};

    float4 ax[2];
    float  bx[4];

    auto load_regs = [&](int ch) {
        int c0 = ch * 32;
        #pragma unroll
        for (int q = 0; q < 2; q++) {
            int c = c0 + a_ci0 + q * 4;
            ax[q] = (c + 4 <= IN_CH) ? *(const float4*)(a_row + c)
                                     : make_float4(0.f, 0.f, 0.f, 0.f);
        }
        #pragma unroll
        for (int i = 0; i < 4; i++) {
            int c = c0 + b_ci0 + i;
            bx[i] = (jvalid && c < IN_CH) ? b_base[(size_t)c * DCLS] : 0.f;
        }
    };

    auto split_write = [&](int buf) {
        unsigned ahi[4], alo[4], bhi[2], blo[2];
        split2(ax[0].x, ax[0].y, ahi[0], alo[0]);
        split2(ax[0].z, ax[0].w, ahi[1], alo[1]);
        split2(ax[1].x, ax[1].y, ahi[2], alo[2]);
        split2(ax[1].z, ax[1].w, ahi[3], alo[3]);
        split2(bx[0], bx[1], bhi[0], blo[0]);
        split2(bx[2], bx[3], bhi[1], blo[1]);
        *(uint4*)((unsigned*)&Ahi[buf][a_bi * RP + a_ci0]) =
            make_uint4(ahi[0], ahi[1], ahi[2], ahi[3]);
        *(uint4*)((unsigned*)&Alo[buf][a_bi * RP + a_ci0]) =
            make_uint4(alo[0], alo[1], alo[2], alo[3]);
        *(uint2*)((unsigned*)&Bhi[buf][b_jj * RP + b_ci0]) =
            make_uint2(bhi[0], bhi[1]);
        *(uint2*)((unsigned*)&Blo[buf][b_jj * RP + b_ci0]) =
            make_uint2(blo[0], blo[1]);
    };

    // prologue: stage chunk 0 into buf 0; prefetch chunk 1 into regs
    load_regs(0);
    split_write(0);
    load_regs(1);            // NCHUNK > 1 always
    __syncthreads();

    for (int ch = 0; ch < NCHUNK; ch++) {
        int cb = ch & 1;

        // ds_read all fragments of current buffer first (issue early)
        short8 Afh[4], Afl[4], Bfh, Bfl;
        #pragma unroll
        for (int mt = 0; mt < 4; mt++) {
            int row = m0w + mt * 16 + lm;
            Afh[mt] = *(const short8*)&Ahi[cb][row * RP + lq * 8];
            Afl[mt] = *(const short8*)&Alo[cb][row * RP + lq * 8];
        }
        {
            int row = n0w + lm;
            Bfh = *(const short8*)&Bhi[cb][row * RP + lq * 8];
            Bfl = *(const short8*)&Blo[cb][row * RP + lq * 8];
        }

        // split chunk ch+1 (regs already loaded) and write to other buffer;
        // then issue global loads for chunk ch+2
        if (ch + 1 < NCHUNK) {
            split_write(cb ^ 1);
            if (ch + 2 < NCHUNK) load_regs(ch + 2);
        }

        // MFMA (j-fragment FIRST: D rows=j, cols=b — transposed C layout)
        #pragma unroll
        for (int mt = 0; mt < 4; mt++) {
            acc[mt] = __builtin_amdgcn_mfma_f32_16x16x32_bf16(
                Bfh, Afh[mt], acc[mt], 0, 0, 0);
            acc[mt] = __builtin_amdgcn_mfma_f32_16x16x32_bf16(
                Bfl, Afh[mt], acc[mt], 0, 0, 0);
            acc[mt] = __builtin_amdgcn_mfma_f32_16x16x32_bf16(
                Bfh, Afl[mt], acc[mt], 0, 0, 0);
        }
        __syncthreads();   // single rendezvous per chunk
    }

    // epilogue (transposed layout): col = lm = b-offset, row = lq*4+r = j
    {
        int jc = j0 + n0w + lq * 4;             // j of reg 0
        if (jc < CAPS * DCLS) {
            int capc = (jc >= 2 * DCLS) ? 2 : ((jc >= DCLS) ? 1 : 0);
            int dc = jc - capc * DCLS;          // dc % 4 == 0, dc+3 <= 199
            #pragma unroll
            for (int mt = 0; mt < 4; mt++) {
                int b = b0 + m0w + mt * 16 + lm;
                float* dst = priors +
                    ((size_t)(capc * BSZ + b) * ADAPTERS + kk) * DCLS + dc;
                *(f4v*)dst = *(f4v*)&acc[mt];
            }
        }
    }
}

// ---------------------------------------------------------------------------
// K2: dynamic routing, one block per (n,b); P[k][d] staged in LDS.
// UNCHANGED (float4 staging, compacted adapter list).
// ---------------------------------------------------------------------------
__global__ __launch_bounds__(256) void k2_route(
    const float* __restrict__ priors,   // [CAPS][B][A][DCLS]
    const float* __restrict__ tsv,
    const int* __restrict__ t_p,
    float* __restrict__ vote)           // [CAPS][B][DCLS]
{
    int nb = blockIdx.x;
    int n = nb >> 8, b = nb & 255;
    int tid = threadIdx.x;
    int lane = tid & 63, wid = tid >> 6;

    __shared__ float Ps[ADAPTERS * DCLS];
    __shared__ float vout[DCLS];
    __shared__ float act[ADAPTERS];
    __shared__ float a_s[ADAPTERS];
    __shared__ float probs_s[ADAPTERS];
    __shared__ int   klist[ADAPTERS];
    __shared__ int   nact_s;
    __shared__ float red[4];
    __shared__ float scl;

    int t = t_p[0];
    if (tid < ADAPTERS) {
        act[tid] = tsv[t * ADAPTERS + tid];
        a_s[tid] = 0.0f;
    }
    __syncthreads();

    if (tid == 0) {
        int c = 0;
        for (int k = 0; k < ADAPTERS; k++)
            if (act[k] != 0.0f) klist[c++] = k;
        nact_s = c;
    }

    {
        const float4* pb4 = (const float4*)
            (priors + (size_t)(n * BSZ + b) * ADAPTERS * DCLS);
        float4* Ps4 = (float4*)Ps;
        for (int i4 = tid; i4 < ADAPTERS * (DCLS / 4); i4 += 256) {
            int k = i4 / (DCLS / 4);
            if (act[k] != 0.0f) Ps4[i4] = pb4[i4];
        }
    }
    __syncthreads();

    int nact = nact_s;
    float cnt = (float)nact;

    int td = tid;
    float v = 0.0f;
    if (td < DCLS) {
        for (int ki = 0; ki < nact; ki++)
            v += Ps[klist[ki] * DCLS + td];
        v /= cnt;
    }

    for (int it = 0; it < 3; it++) {
        if (it > 0) {
            if (wid == 0) {
                bool on = (lane < ADAPTERS) && (act[lane] != 0.f);
                float val = on ? a_s[lane] : -3.0e38f;
                float m = val;
                for (int off = 32; off; off >>= 1)
                    m = fmaxf(m, __shfl_down(m, off));
                m = __shfl(m, 0);
                float e = on ? expf(val - m) : 0.f;
                float ssum = e;
                for (int off = 32; off; off >>= 1)
                    ssum += __shfl_down(ssum, off);
                ssum = __shfl(ssum, 0);
                if (lane < ADAPTERS) probs_s[lane] = e / ssum;
            }
            __syncthreads();
            v = 0.0f;
            if (td < DCLS) {
                for (int ki = 0; ki < nact; ki++) {
                    int k = klist[ki];
                    v += probs_s[k] * Ps[k * DCLS + td];
                }
            }
        }
        if (it == 2) break;

        float vv = (td < DCLS) ? v * v : 0.f;
        for (int off = 32; off; off >>= 1) vv += __shfl_down(vv, off);
        if (lane == 0) red[wid] = vv;
        __syncthreads();
        if (tid == 0) {
            float sq = red[0] + red[1] + red[2] + red[3];
            scl = sqrtf(sq) / (1.0f + sq);
        }
        __syncthreads();
        if (td < DCLS) vout[td] = v * scl;
        __syncthreads();

        for (int ki = wid; ki < nact; ki += 4) {
            int k = klist[ki];
            const float* row = Ps + k * DCLS;
            float p = row[lane] * vout[lane]
                    + row[lane + 64] * vout[lane + 64]
                    + row[lane + 128] * vout[lane + 128];
            if (lane < DCLS - 192) p += row[lane + 192] * vout[lane + 192];
            for (int off = 32; off; off >>= 1) p += __shfl_down(p, off);
            if (lane == 0) a_s[k] += p;
        }
        __syncthreads();
    }

    if (td < DCLS) vote[(size_t)n * BSZ * DCLS + b * DCLS + td] = v;
}

// ---------------------------------------------------------------------------
// K3 (includes k0's gating): out[row][j] =
//   sum_c vote_flat[row*3+c] * g(j)*lw[j][c]  +  g(j)*lb[j]
// UNCHANGED.
// ---------------------------------------------------------------------------
__global__ __launch_bounds__(256) void k3_out(
    const float* __restrict__ vote,     // [3*256*200] flat
    const float* __restrict__ s_p,
    const float* __restrict__ lw,       // [DMODEL][3]
    const float* __restrict__ lb,       // [DMODEL]
    const float* __restrict__ el,       // [A][DMODEL]
    const int* __restrict__ t_p,
    float* __restrict__ out)            // [51200][768]
{
    __shared__ float vs[192];
    int tid = threadIdx.x;
    int r0 = blockIdx.x * 64;
    if (tid < 192) vs[tid] = vote[r0 * 3 + tid];

    int lane = tid & 63;
    int ty = tid >> 6;
    int j = blockIdx.y * 256 + lane * 4;

    int t = t_p[0];
    float s = s_p[0];
    float4 e4  = *(const float4*)(el + (size_t)t * DMODEL + j);
    float4 lb4 = *(const float4*)(lb + j);
    const float4* lw4 = (const float4*)(lw + (size_t)j * 3);  // 48B-aligned
    float4 w0 = lw4[0], w1 = lw4[1], w2 = lw4[2];
    float ga = 1.0f / (1.0f + expf(-s * e4.x));
    float gb = 1.0f / (1.0f + expf(-s * e4.y));
    float gc = 1.0f / (1.0f + expf(-s * e4.z));
    float gd = 1.0f / (1.0f + expf(-s * e4.w));
    float4 g0 = make_float4(ga * w0.x, ga * w0.y, ga * w0.z, ga * lb4.x);
    float4 g1 = make_float4(gb * w0.w, gb * w1.x, gb * w1.y, gb * lb4.y);
    float4 g2 = make_float4(gc * w1.z, gc * w1.w, gc * w2.x, gc * lb4.z);
    float4 g3 = make_float4(gd * w2.y, gd * w2.z, gd * w2.w, gd * lb4.w);

    __syncthreads();

    #pragma unroll
    for (int it = 0; it < 16; it++) {
        int rl = it * 4 + ty;
        float h0 = vs[rl * 3 + 0];
        float h1 = vs[rl * 3 + 1];
        float h2 = vs[rl * 3 + 2];
        f4v o;
        o.x = h0 * g0.x + h1 * g0.y + h2 * g0.z + g0.w;
        o.y = h0 * g1.x + h1 * g1.y + h2 * g1.z + g1.w;
        o.z = h0 * g2.x + h1 * g2.y + h2 * g2.z + g2.w;
        o.w = h0 * g3.x + h1 * g3.y + h2 * g3.z + g3.w;
        __builtin_nontemporal_store(o, (f4v*)(out + (size_t)(r0 + rl) * DMODEL + j));
    }
}

// ---------------------------------------------------------------------------
extern "C" void kernel_launch(void* const* d_in, const int* in_sizes, int n_in,
                              void* d_out, int out_size, void* d_ws, size_t ws_size,
                              hipStream_t stream) {
    const int*   t   = (const int*)d_in[0];
    const float* x   = (const float*)d_in[1];
    const float* s   = (const float*)d_in[2];
    const float* rw  = (const float*)d_in[3];
    const float* lw  = (const float*)d_in[4];
    const float* lb  = (const float*)d_in[5];
    const float* el  = (const float*)d_in[6];
    const float* tsv = (const float*)d_in[7];
    float* out = (float*)d_out;

    char* wsb = (char*)d_ws;
    float* priors = (float*)wsb;                // 24,576,000 B
    float* vote   = (float*)(wsb + 24576000);   // 614,400 B

    k1_priors<<<dim3(2, 10, ADAPTERS), dim3(512), 0, stream>>>(x, rw, tsv, t, priors);
    k2_route<<<dim3(CAPS * BSZ), dim3(256), 0, stream>>>(priors, tsv, t, vote);
    k3_out<<<dim3(BSZ * DCLS / 64, 3), dim3(256), 0, stream>>>(vote, s, lw, lb, el, t, out);
}

// Round 7
// 270.784 us; speedup vs baseline: 1.0277x; 1.0277x over previous
//
#include <hip/hip_runtime.h>
#include <hip/hip_bf16.h>

#define ADAPTERS 40
#define CAPS 3
#define IN_CH 600
#define BSZ 256
#define DCLS 200
#define DMODEL 768

typedef __attribute__((ext_vector_type(8))) short short8;   // 8 bf16
typedef __attribute__((ext_vector_type(4))) float f32x4;
typedef __attribute__((ext_vector_type(4))) float f4v;

// ---------------------------------------------------------------------------
// K1 (MFMA): priors[cap][b][k][d] = sum_c x[b][k][c] * rw[k][cap][c][d]
// f32 inputs split into bf16 hi/lo; D += hi*hi + lo*hi + hi*lo
// (error ~2^-16 relative — f32-equivalent).
// REVERT to round-5 config (best measured: 273.4 µs): 128x128 tile,
// 512 threads, LDS double-buffered, ONE barrier per chunk.  Round 6's
// 128x64 tile (2 blocks/CU) regressed +4.9 µs: halving the j-tile doubled
// the redundant A-staging traffic + split2 VALU work, exceeding the
// barrier-overlap gain.  // lever boundary: co-resident barrier domains
// help only at constant total staging work.
// ---------------------------------------------------------------------------
#define RP 40          // LDS row pitch in ushorts (32 data + 8 pad = 80 B)
#define NCHUNK 19

__device__ __forceinline__ void split2(float f0, float f1,
                                       unsigned& hi, unsigned& lo) {
    unsigned u0 = __float_as_uint(f0), u1 = __float_as_uint(f1);
    unsigned h0 = u0 & 0xFFFF0000u, h1 = u1 & 0xFFFF0000u;
    hi = (u0 >> 16) | h1;
    float l0 = f0 - __uint_as_float(h0);
    float l1 = f1 - __uint_as_float(h1);
    lo = (__float_as_uint(l0) >> 16) | (__float_as_uint(l1) & 0xFFFF0000u);
}

__global__ __launch_bounds__(512) void k1_priors(
    const float* __restrict__ x,    // [B][A][IN_CH]
    const float* __restrict__ rw,   // [A][CAPS][IN_CH][DCLS]
    const float* __restrict__ tsv,  // [A][A]
    const int* __restrict__ t_p,
    float* __restrict__ priors)     // [CAPS][B][A][DCLS]
{
    int kk = blockIdx.z;            // adapter
    int t = t_p[0];
    if (tsv[t * ADAPTERS + kk] == 0.0f) return;

    int b0 = blockIdx.x * 128;      // 0 or 128
    int j0 = blockIdx.y * 128;      // 0..512

    // double-buffered: [buf][row*RP]  (4 arrays x 2 x 10 KB = 80 KB)
    __shared__ __align__(16) unsigned short Ahi[2][128 * RP];
    __shared__ __align__(16) unsigned short Alo[2][128 * RP];
    __shared__ __align__(16) unsigned short Bhi[2][128 * RP];
    __shared__ __align__(16) unsigned short Blo[2][128 * RP];

    int tid = threadIdx.x;
    int lane = tid & 63, w = tid >> 6;          // w = 0..7
    int lm = lane & 15, lq = lane >> 4;
    int m0w = (w & 1) * 64;                     // b-half
    int n0w = (w >> 1) * 32;                    // j-quarter

    // ---- staging thread maps (512 threads) ----
    int a_bi = tid >> 2;
    int a_ci0 = (tid & 3) * 8;
    const float* a_row = x + ((size_t)(b0 + a_bi) * ADAPTERS + kk) * IN_CH;
    int b_jj = tid >> 2;
    int b_ci0 = (tid & 3) * 8;
    int j = j0 + b_jj;
    bool jvalid = (j < CAPS * DCLS);
    int cap = (j >= 2 * DCLS) ? 2 : ((j >= DCLS) ? 1 : 0);
    int d = j - cap * DCLS;
    const float* b_base = rw + ((size_t)(kk * 3 + cap) * IN_CH) * DCLS + d;

    f32x4 acc[4][2];
    #pragma unroll
    for (int mt = 0; mt < 4; mt++)
        #pragma unroll
        for (int nt = 0; nt < 2; nt++)
            acc[mt][nt] = (f32x4){0.f, 0.f, 0.f, 0.f};

    float4 ax[2];
    float  bx[8];

    auto load_regs = [&](int ch) {
        int c0 = ch * 32;
        #pragma unroll
        for (int q = 0; q < 2; q++) {
            int c = c0 + a_ci0 + q * 4;
            ax[q] = (c + 4 <= IN_CH) ? *(const float4*)(a_row + c)
                                     : make_float4(0.f, 0.f, 0.f, 0.f);
        }
        #pragma unroll
        for (int i = 0; i < 8; i++) {
            int c = c0 + b_ci0 + i;
            bx[i] = (jvalid && c < IN_CH) ? b_base[(size_t)c * DCLS] : 0.f;
        }
    };

    auto split_write = [&](int buf) {
        unsigned ahi[4], alo[4], bhi[4], blo[4];
        split2(ax[0].x, ax[0].y, ahi[0], alo[0]);
        split2(ax[0].z, ax[0].w, ahi[1], alo[1]);
        split2(ax[1].x, ax[1].y, ahi[2], alo[2]);
        split2(ax[1].z, ax[1].w, ahi[3], alo[3]);
        #pragma unroll
        for (int p = 0; p < 4; p++)
            split2(bx[2 * p], bx[2 * p + 1], bhi[p], blo[p]);
        *(uint4*)((unsigned*)&Ahi[buf][a_bi * RP + a_ci0]) =
            make_uint4(ahi[0], ahi[1], ahi[2], ahi[3]);
        *(uint4*)((unsigned*)&Alo[buf][a_bi * RP + a_ci0]) =
            make_uint4(alo[0], alo[1], alo[2], alo[3]);
        *(uint4*)((unsigned*)&Bhi[buf][b_jj * RP + b_ci0]) =
            make_uint4(bhi[0], bhi[1], bhi[2], bhi[3]);
        *(uint4*)((unsigned*)&Blo[buf][b_jj * RP + b_ci0]) =
            make_uint4(blo[0], blo[1], blo[2], blo[3]);
    };

    // prologue: stage chunk 0 into buf 0; prefetch chunk 1 into regs
    load_regs(0);
    split_write(0);
    load_regs(1);            // NCHUNK > 1 always
    __syncthreads();

    for (int ch = 0; ch < NCHUNK; ch++) {
        int cb = ch & 1;

        // ds_read all fragments of current buffer first (issue early)
        short8 Afh[4], Afl[4], Bfh[2], Bfl[2];
        #pragma unroll
        for (int mt = 0; mt < 4; mt++) {
            int row = m0w + mt * 16 + lm;
            Afh[mt] = *(const short8*)&Ahi[cb][row * RP + lq * 8];
            Afl[mt] = *(const short8*)&Alo[cb][row * RP + lq * 8];
        }
        #pragma unroll
        for (int nt = 0; nt < 2; nt++) {
            int row = n0w + nt * 16 + lm;
            Bfh[nt] = *(const short8*)&Bhi[cb][row * RP + lq * 8];
            Bfl[nt] = *(const short8*)&Blo[cb][row * RP + lq * 8];
        }

        // split chunk ch+1 (regs already loaded) and write to other buffer;
        // then issue global loads for chunk ch+2
        if (ch + 1 < NCHUNK) {
            split_write(cb ^ 1);
            if (ch + 2 < NCHUNK) load_regs(ch + 2);
        }

        // MFMA (j-fragment FIRST: D rows=j, cols=b — transposed C layout)
        #pragma unroll
        for (int nt = 0; nt < 2; nt++) {
            #pragma unroll
            for (int mt = 0; mt < 4; mt++) {
                acc[mt][nt] = __builtin_amdgcn_mfma_f32_16x16x32_bf16(
                    Bfh[nt], Afh[mt], acc[mt][nt], 0, 0, 0);
                acc[mt][nt] = __builtin_amdgcn_mfma_f32_16x16x32_bf16(
                    Bfl[nt], Afh[mt], acc[mt][nt], 0, 0, 0);
                acc[mt][nt] = __builtin_amdgcn_mfma_f32_16x16x32_bf16(
                    Bfh[nt], Afl[mt], acc[mt][nt], 0, 0, 0);
            }
        }
        __syncthreads();   // single rendezvous per chunk
    }

    // epilogue (transposed layout): col = lm = b-offset, row = lq*4+r = j
    #pragma unroll
    for (int nt = 0; nt < 2; nt++) {
        int jc = j0 + n0w + nt * 16 + lq * 4;   // j of reg 0
        if (jc >= CAPS * DCLS) continue;
        int capc = (jc >= 2 * DCLS) ? 2 : ((jc >= DCLS) ? 1 : 0);
        int dc = jc - capc * DCLS;              // dc % 4 == 0, dc+3 <= 199
        #pragma unroll
        for (int mt = 0; mt < 4; mt++) {
            int b = b0 + m0w + mt * 16 + lm;
            float* dst = priors +
                ((size_t)(capc * BSZ + b) * ADAPTERS + kk) * DCLS + dc;
            *(f4v*)dst = *(f4v*)&acc[mt][nt];
        }
    }
}

// ---------------------------------------------------------------------------
// K2: dynamic routing, one block per (n,b); P[k][d] staged in LDS.
// UNCHANGED (float4 staging, compacted adapter list).
// ---------------------------------------------------------------------------
__global__ __launch_bounds__(256) void k2_route(
    const float* __restrict__ priors,   // [CAPS][B][A][DCLS]
    const float* __restrict__ tsv,
    const int* __restrict__ t_p,
    float* __restrict__ vote)           // [CAPS][B][DCLS]
{
    int nb = blockIdx.x;
    int n = nb >> 8, b = nb & 255;
    int tid = threadIdx.x;
    int lane = tid & 63, wid = tid >> 6;

    __shared__ float Ps[ADAPTERS * DCLS];
    __shared__ float vout[DCLS];
    __shared__ float act[ADAPTERS];
    __shared__ float a_s[ADAPTERS];
    __shared__ float probs_s[ADAPTERS];
    __shared__ int   klist[ADAPTERS];
    __shared__ int   nact_s;
    __shared__ float red[4];
    __shared__ float scl;

    int t = t_p[0];
    if (tid < ADAPTERS) {
        act[tid] = tsv[t * ADAPTERS + tid];
        a_s[tid] = 0.0f;
    }
    __syncthreads();

    if (tid == 0) {
        int c = 0;
        for (int k = 0; k < ADAPTERS; k++)
            if (act[k] != 0.0f) klist[c++] = k;
        nact_s = c;
    }

    {
        const float4* pb4 = (const float4*)
            (priors + (size_t)(n * BSZ + b) * ADAPTERS * DCLS);
        float4* Ps4 = (float4*)Ps;
        for (int i4 = tid; i4 < ADAPTERS * (DCLS / 4); i4 += 256) {
            int k = i4 / (DCLS / 4);
            if (act[k] != 0.0f) Ps4[i4] = pb4[i4];
        }
    }
    __syncthreads();

    int nact = nact_s;
    float cnt = (float)nact;

    int td = tid;
    float v = 0.0f;
    if (td < DCLS) {
        for (int ki = 0; ki < nact; ki++)
            v += Ps[klist[ki] * DCLS + td];
        v /= cnt;
    }

    for (int it = 0; it < 3; it++) {
        if (it > 0) {
            if (wid == 0) {
                bool on = (lane < ADAPTERS) && (act[lane] != 0.f);
                float val = on ? a_s[lane] : -3.0e38f;
                float m = val;
                for (int off = 32; off; off >>= 1)
                    m = fmaxf(m, __shfl_down(m, off));
                m = __shfl(m, 0);
                float e = on ? expf(val - m) : 0.f;
                float ssum = e;
                for (int off = 32; off; off >>= 1)
                    ssum += __shfl_down(ssum, off);
                ssum = __shfl(ssum, 0);
                if (lane < ADAPTERS) probs_s[lane] = e / ssum;
            }
            __syncthreads();
            v = 0.0f;
            if (td < DCLS) {
                for (int ki = 0; ki < nact; ki++) {
                    int k = klist[ki];
                    v += probs_s[k] * Ps[k * DCLS + td];
                }
            }
        }
        if (it == 2) break;

        float vv = (td < DCLS) ? v * v : 0.f;
        for (int off = 32; off; off >>= 1) vv += __shfl_down(vv, off);
        if (lane == 0) red[wid] = vv;
        __syncthreads();
        if (tid == 0) {
            float sq = red[0] + red[1] + red[2] + red[3];
            scl = sqrtf(sq) / (1.0f + sq);
        }
        __syncthreads();
        if (td < DCLS) vout[td] = v * scl;
        __syncthreads();

        for (int ki = wid; ki < nact; ki += 4) {
            int k = klist[ki];
            const float* row = Ps + k * DCLS;
            float p = row[lane] * vout[lane]
                    + row[lane + 64] * vout[lane + 64]
                    + row[lane + 128] * vout[lane + 128];
            if (lane < DCLS - 192) p += row[lane + 192] * vout[lane + 192];
            for (int off = 32; off; off >>= 1) p += __shfl_down(p, off);
            if (lane == 0) a_s[k] += p;
        }
        __syncthreads();
    }

    if (td < DCLS) vote[(size_t)n * BSZ * DCLS + b * DCLS + td] = v;
}

// ---------------------------------------------------------------------------
// K3 (includes k0's gating): out[row][j] =
//   sum_c vote_flat[row*3+c] * g(j)*lw[j][c]  +  g(j)*lb[j]
// UNCHANGED.
// ---------------------------------------------------------------------------
__global__ __launch_bounds__(256) void k3_out(
    const float* __restrict__ vote,     // [3*256*200] flat
    const float* __restrict__ s_p,
    const float* __restrict__ lw,       // [DMODEL][3]
    const float* __restrict__ lb,       // [DMODEL]
    const float* __restrict__ el,       // [A][DMODEL]
    const int* __restrict__ t_p,
    float* __restrict__ out)            // [51200][768]
{
    __shared__ float vs[192];
    int tid = threadIdx.x;
    int r0 = blockIdx.x * 64;
    if (tid < 192) vs[tid] = vote[r0 * 3 + tid];

    int lane = tid & 63;
    int ty = tid >> 6;
    int j = blockIdx.y * 256 + lane * 4;

    int t = t_p[0];
    float s = s_p[0];
    float4 e4  = *(const float4*)(el + (size_t)t * DMODEL + j);
    float4 lb4 = *(const float4*)(lb + j);
    const float4* lw4 = (const float4*)(lw + (size_t)j * 3);  // 48B-aligned
    float4 w0 = lw4[0], w1 = lw4[1], w2 = lw4[2];
    float ga = 1.0f / (1.0f + expf(-s * e4.x));
    float gb = 1.0f / (1.0f + expf(-s * e4.y));
    float gc = 1.0f / (1.0f + expf(-s * e4.z));
    float gd = 1.0f / (1.0f + expf(-s * e4.w));
    float4 g0 = make_float4(ga * w0.x, ga * w0.y, ga * w0.z, ga * lb4.x);
    float4 g1 = make_float4(gb * w0.w, gb * w1.x, gb * w1.y, gb * lb4.y);
    float4 g2 = make_float4(gc * w1.z, gc * w1.w, gc * w2.x, gc * lb4.z);
    float4 g3 = make_float4(gd * w2.y, gd * w2.z, gd * w2.w, gd * lb4.w);

    __syncthreads();

    #pragma unroll
    for (int it = 0; it < 16; it++) {
        int rl = it * 4 + ty;
        float h0 = vs[rl * 3 + 0];
        float h1 = vs[rl * 3 + 1];
        float h2 = vs[rl * 3 + 2];
        f4v o;
        o.x = h0 * g0.x + h1 * g0.y + h2 * g0.z + g0.w;
        o.y = h0 * g1.x + h1 * g1.y + h2 * g1.z + g1.w;
        o.z = h0 * g2.x + h1 * g2.y + h2 * g2.z + g2.w;
        o.w = h0 * g3.x + h1 * g3.y + h2 * g3.z + g3.w;
        __builtin_nontemporal_store(o, (f4v*)(out + (size_t)(r0 + rl) * DMODEL + j));
    }
}

// ---------------------------------------------------------------------------
extern "C" void kernel_launch(void* const* d_in, const int* in_sizes, int n_in,
                              void* d_out, int out_size, void* d_ws, size_t ws_size,
                              hipStream_t stream) {
    const int*   t   = (const int*)d_in[0];
    const float* x   = (const float*)d_in[1];
    const float* s   = (const float*)d_in[2];
    const float* rw  = (const float*)d_in[3];
    const float* lw  = (const float*)d_in[4];
    const float* lb  = (const float*)d_in[5];
    const float* el  = (const float*)d_in[6];
    const float* tsv = (const float*)d_in[7];
    float* out = (float*)d_out;

    char* wsb = (char*)d_ws;
    float* priors = (float*)wsb;                // 24,576,000 B
    float* vote   = (float*)(wsb + 24576000);   // 614,400 B

    k1_priors<<<dim3(2, 5, ADAPTERS), dim3(512), 0, stream>>>(x, rw, tsv, t, priors);
    k2_route<<<dim3(CAPS * BSZ), dim3(256), 0, stream>>>(priors, tsv, t, vote);
    k3_out<<<dim3(BSZ * DCLS / 64, 3), dim3(256), 0, stream>>>(vote, s, lw, lb, el, t, out);
}